// Round 1
// baseline (4914.696 us; speedup 1.0000x reference)
//
#include <hip/hip_runtime.h>
#include <hip/hip_bf16.h>
#include <math.h>

// Problem constants
#define BB 64
#define LL 200
#define NQ 1024
#define DD 256
#define HH 512
#define QQ 1024
#define G3 1536   // 3*H
#define BL 12800  // B*L

// ---------------- workspace layout (in floats) ----------------
#define OFF_ACC   ((size_t)0)                    // 4 floats: [0]=creg_raw [1]=mse [2]=maskcnt
#define OFF_H0    ((size_t)4)                    // 512*64
#define OFF_AQ    (OFF_H0 + 32768)               // 1025*1536
#define OFF_DQ    (OFF_AQ + 1574400)             // 1025*1536
#define OFF_BQA   (OFF_DQ + 1574400)             // 2*1536
#define OFF_CQA   (OFF_BQA + 3072)               // 2*1536
#define OFF_WSUM  (OFF_CQA + 3072)               // 1536*256
#define OFF_FCWT  (OFF_WSUM + 393216)            // 512*1024
#define OFF_M2    (OFF_FCWT + 524288)            // 1024*512
#define OFF_MB    (OFF_M2 + 524288)              // 1024
#define OFF_XG    (OFF_MB + 1024)                // 12800*1536  [L][B][1536] row=(t*64+b)
#define OFF_GRU   (OFF_XG + 19660800)            // 200*512*64  [t][k][b]
#define OFF_QINT  (OFF_GRU + 6553600)            // 12800 ints [B][L]
#define OFF_QAINT (OFF_QINT + 12800)             // 12800 ints
#define OFF_PIDF  (OFF_QAINT + 12800)            // 12800 floats
#define OFF_MVAL  (OFF_PIDF + 12800)
#define OFF_MC    (OFF_MVAL + 12800)
#define OFF_MI    (OFF_MC + 12800)
#define OFF_NMC   (OFF_MI + 12800)
#define OFF_AA    (OFF_NMC + 12800)
#define OFF_PREDS (OFF_AA + 12800)

__device__ __forceinline__ float wave_sum64(float v) {
    #pragma unroll
    for (int o = 32; o > 0; o >>= 1) v += __shfl_down(v, o, 64);
    return v;
}

// -------- meta: q, qa, pid per (b,t); c_reg accumulation --------
__global__ __launch_bounds__(256) void prep_meta(
    const int* __restrict__ q_data, const int* __restrict__ qa_data,
    const int* __restrict__ pid_data, const float* __restrict__ diff_parm,
    int* __restrict__ qint, int* __restrict__ qaint, float* __restrict__ pidf,
    float* __restrict__ acc)
{
    int r = blockIdx.x * 256 + threadIdx.x;
    float pp = 0.f;
    if (r < BL) {
        int q = q_data[r];
        qint[r] = q;
        qaint[r] = (qa_data[r] - q) / NQ;
        float pid = diff_parm[pid_data[r]];
        pidf[r] = pid;
        pp = pid * pid;
    }
    pp = wave_sum64(pp);
    __shared__ float sm[4];
    int lane = threadIdx.x & 63, w = threadIdx.x >> 6;
    if (lane == 0) sm[w] = pp;
    __syncthreads();
    if (threadIdx.x == 0) atomicAdd(&acc[0], sm[0] + sm[1] + sm[2] + sm[3]);
}

// -------- wsum[g,d] = w_ih[g,d] + w_ih[g,256+d] --------
__global__ __launch_bounds__(256) void wsum_kernel(const float* __restrict__ w_ih,
                                                   float* __restrict__ wsum)
{
    int g = blockIdx.x, d = threadIdx.x;   // 1536 blocks x 256
    wsum[(size_t)g * DD + d] = w_ih[(size_t)g * 2 * DD + d] + w_ih[(size_t)g * 2 * DD + DD + d];
}

// -------- transpose [R,C] -> [C,R] --------
__global__ __launch_bounds__(256) void transpose_kernel(const float* __restrict__ in,
                                                        float* __restrict__ out, int R, int C)
{
    __shared__ float tile[32][33];
    int r0 = blockIdx.y * 32, c0 = blockIdx.x * 32;
    int tx = threadIdx.x & 31, ty = threadIdx.x >> 5;  // ty 0..7
    #pragma unroll
    for (int i = 0; i < 32; i += 8) {
        int r = r0 + ty + i, c = c0 + tx;
        if (r < R && c < C) tile[ty + i][tx] = in[(size_t)r * C + c];
    }
    __syncthreads();
    #pragma unroll
    for (int i = 0; i < 32; i += 8) {
        int c = c0 + ty + i, r = r0 + tx;
        if (c < C && r < R) out[(size_t)c * R + r] = tile[tx][ty + i];
    }
}

// -------- generic NT GEMM: C[m,n] = sum_k A[m,k]*B[n,k] (+bias[n]) --------
__global__ __launch_bounds__(256) void gemm_nt(
    const float* __restrict__ A, int lda,
    const float* __restrict__ B, int ldb,
    float* __restrict__ C, int ldc,
    int M, int N, int K, const float* __restrict__ bias)
{
    __shared__ float As[16][65];
    __shared__ float Bs[16][65];
    const int bm = blockIdx.y * 64, bn = blockIdx.x * 64;
    const int tid = threadIdx.x;
    const int tx = tid & 15, ty = tid >> 4;
    float acc[4][4] = {};
    for (int k0 = 0; k0 < K; k0 += 16) {
        #pragma unroll
        for (int i = 0; i < 4; ++i) {
            int e = tid + i * 256;
            int mm = e >> 4, kk = e & 15;
            int m = bm + mm;
            As[kk][mm] = (m < M) ? A[(size_t)m * lda + k0 + kk] : 0.f;
            int n = bn + mm;
            Bs[kk][mm] = (n < N) ? B[(size_t)n * ldb + k0 + kk] : 0.f;
        }
        __syncthreads();
        #pragma unroll
        for (int kk = 0; kk < 16; ++kk) {
            float a[4], b[4];
            #pragma unroll
            for (int i = 0; i < 4; ++i) a[i] = As[kk][ty * 4 + i];
            #pragma unroll
            for (int j = 0; j < 4; ++j) b[j] = Bs[kk][tx * 4 + j];
            #pragma unroll
            for (int i = 0; i < 4; ++i)
                #pragma unroll
                for (int j = 0; j < 4; ++j) acc[i][j] += a[i] * b[j];
        }
        __syncthreads();
    }
    #pragma unroll
    for (int i = 0; i < 4; ++i) {
        int m = bm + ty * 4 + i;
        if (m >= M) continue;
        #pragma unroll
        for (int j = 0; j < 4; ++j) {
            int n = bn + tx * 4 + j;
            if (n >= N) continue;
            C[(size_t)m * ldc + n] = acc[i][j] + (bias ? bias[n] : 0.f);
        }
    }
}

// -------- mb[k] = sum_q matrix[k,q]*fc_b[q] --------
__global__ __launch_bounds__(256) void mb_kernel(const float* __restrict__ matrix,
                                                 const float* __restrict__ fc_b,
                                                 float* __restrict__ mb)
{
    int k = blockIdx.x;
    float s = 0.f;
    for (int q = threadIdx.x; q < QQ; q += 256) s += matrix[(size_t)k * QQ + q] * fc_b[q];
    s = wave_sum64(s);
    __shared__ float sm[4];
    int lane = threadIdx.x & 63, w = threadIdx.x >> 6;
    if (lane == 0) sm[w] = s;
    __syncthreads();
    if (threadIdx.x == 0) mb[k] = sm[0] + sm[1] + sm[2] + sm[3];
}

// -------- xg gather: xg[(t*64+b), g] = A_q[q,g]+B_qa[qa,g]+pid*(C_qa[qa,g]+D_q[q,g]) --------
__global__ __launch_bounds__(256) void xg_kernel(
    const float* __restrict__ Aq, const float* __restrict__ Bqa,
    const float* __restrict__ Cqa, const float* __restrict__ Dq,
    const int* __restrict__ qint, const int* __restrict__ qaint,
    const float* __restrict__ pidf, float* __restrict__ xg)
{
    int blk = blockIdx.x;              // t*64 + b
    int t = blk >> 6, b = blk & 63;
    int rm = b * LL + t;
    int q = qint[rm], qa = qaint[rm];
    float pid = pidf[rm];
    const float* aq = Aq + (size_t)q * G3;
    const float* dq = Dq + (size_t)q * G3;
    const float* bq = Bqa + (size_t)qa * G3;
    const float* cq = Cqa + (size_t)qa * G3;
    float* o = xg + (size_t)blk * G3;
    for (int g = threadIdx.x; g < G3; g += 256)
        o[g] = aq[g] + bq[g] + pid * (cq[g] + dq[g]);
}

// -------- one GRU step: 256 blocks, each owns 2 hidden units for all 64 batches --------
__global__ __launch_bounds__(128) void gru_step(
    const float* __restrict__ hprev,   // [512][64]
    const float* __restrict__ xg_t,    // [64][1536]
    const float* __restrict__ w_hh,    // [1536][512]
    const float* __restrict__ b_hh,    // [1536]
    float* __restrict__ hout)          // [512][64]
{
    __shared__ float wsm[6][512];      // rr = gate*2 + jj
    const int tid = threadIdx.x;
    const int b = tid & 63, jj = tid >> 6;   // jj 0..1
    const int j0 = blockIdx.x * 2;
    for (int i = tid; i < 6 * 512; i += 128) {
        int rr = i >> 9, k = i & 511;
        int gate = rr >> 1, jq = rr & 1;
        wsm[rr][k] = w_hh[(size_t)(gate * HH + j0 + jq) * HH + k];
    }
    __syncthreads();
    const int j = j0 + jj;
    float xr = xg_t[(size_t)b * G3 + j];
    float xz = xg_t[(size_t)b * G3 + HH + j];
    float xn = xg_t[(size_t)b * G3 + 2 * HH + j];
    float hj = hprev[j * BB + b];
    const float* wr = wsm[0 + jj];
    const float* wz = wsm[2 + jj];
    const float* wn = wsm[4 + jj];
    float ar = 0.f, az = 0.f, an = 0.f;
    #pragma unroll 8
    for (int k = 0; k < HH; ++k) {
        float h = hprev[k * BB + b];
        ar += wr[k] * h;
        az += wz[k] * h;
        an += wn[k] * h;
    }
    float rg = 1.f / (1.f + expf(-(xr + ar + b_hh[j])));
    float zg = 1.f / (1.f + expf(-(xz + az + b_hh[HH + j])));
    float ng = tanhf(xn + rg * (an + b_hh[2 * HH + j]));
    hout[j * BB + b] = (1.f - zg) * ng + zg * hj;
}

// -------- mvals[b,t] = threshold( dot(h_t, M2[q-1]) + mb[q-1] ) --------
__global__ __launch_bounds__(64) void mval_kernel(
    const float* __restrict__ gruT,    // [200][512][64]
    const float* __restrict__ M2,      // [1024][512]
    const float* __restrict__ mb,      // [1024]
    const int* __restrict__ qint,      // [B][L]
    float* __restrict__ mval)          // [B][L]
{
    int t = blockIdx.x, b = threadIdx.x;
    int q = qint[b * LL + t] - 1;
    float acc = mb[q];
    const float* hp = gruT + (size_t)t * HH * BB;
    const float* m2 = M2 + (size_t)q * HH;
    #pragma unroll 4
    for (int k = 0; k < HH; ++k)
        acc += hp[k * BB + b] * m2[k];
    mval[b * LL + t] = (acc >= 0.4f) ? 1.0f : acc;
}

// -------- per-(b,t) counting statistics --------
__global__ __launch_bounds__(256) void stats_kernel(
    const int* __restrict__ qint, const int* __restrict__ qaint,
    const float* __restrict__ mval,
    float* __restrict__ mc, float* __restrict__ mi,
    float* __restrict__ nmc, float* __restrict__ aa)
{
    int b = blockIdx.x, tid = threadIdx.x;
    __shared__ int qs[LL];
    __shared__ int qas[LL];
    __shared__ float mv[LL];
    if (tid < LL) {
        qs[tid] = qint[b * LL + tid];
        qas[tid] = qaint[b * LL + tid];
        mv[tid] = mval[b * LL + tid];
    }
    __syncthreads();
    int t = tid;
    if (t < LL) {
        int qt = qs[t];
        float smc = 0.f, smi = 0.f, snmc = 0.f, saa = 0.f;
        for (int k = 0; k <= t; ++k) {
            if (qs[k] == qt) {
                saa += 1.f;
                if (k < t) {
                    float mk = (mv[k] == 1.f) ? 1.f : 0.f;
                    float nk = (mv[k] == 0.f) ? 1.f : 0.f;
                    float a1 = (qas[k] == 1) ? 1.f : 0.f;
                    smc += a1 * mk;
                    smi += (1.f - a1) * mk;
                    snmc += (1.f - a1) * nk;
                }
            }
        }
        mc[b * LL + t] = smc;
        mi[b * LL + t] = smi;
        nmc[b * LL + t] = snmc;
        aa[b * LL + t] = saa;
    }
}

// -------- sequential DINA scan per batch --------
__global__ __launch_bounds__(256) void dina_kernel(
    const int* __restrict__ qint, const int* __restrict__ qaint,
    const float* __restrict__ mval,
    const float* __restrict__ mc, const float* __restrict__ mi,
    const float* __restrict__ nmc, const float* __restrict__ aa,
    float* __restrict__ preds)
{
    int b = blockIdx.x, tid = threadIdx.x;
    __shared__ float guess[QQ], slip[QQ];
    __shared__ float s_m[LL], s_mc[LL], s_mi[LL], s_nmc[LL], s_aa[LL];
    __shared__ int s_i[LL], s_qa[LL];
    for (int i = tid; i < QQ; i += 256) { guess[i] = 0.f; slip[i] = 0.f; }
    if (tid < LL) {
        s_m[tid] = mval[b * LL + tid];
        s_mc[tid] = mc[b * LL + tid];
        s_mi[tid] = mi[b * LL + tid];
        s_nmc[tid] = nmc[b * LL + tid];
        s_aa[tid] = aa[b * LL + tid];
        s_i[tid] = qint[b * LL + tid] - 1;
        s_qa[tid] = qaint[b * LL + tid];
    }
    __syncthreads();
    if (tid == 0) {
        for (int t = 0; t < LL; ++t) {
            int i = s_i[t];
            float m = s_m[t];
            int qa = s_qa[t];
            float aat = s_aa[t];
            float g_upd = (m == 1.f) ? s_mc[t] / aat
                          : ((qa == 0) ? 1.f - s_nmc[t] / aat : s_nmc[t] / aat);
            bool us = (m == 1.f) && (qa == 0);
            float ng = us ? guess[i] : g_upd;
            float ns = us ? s_mi[t] / aat : slip[i];
            guess[i] = ng;
            slip[i] = ns;
            preds[b * LL + t] = (1.f - ns) * (m * ng + (1.f - ns) * (1.f - m));
        }
    }
}

// -------- masked MSE + sigmoid outputs --------
__global__ __launch_bounds__(256) void loss_kernel(
    const float* __restrict__ preds, const float* __restrict__ target,
    float* __restrict__ out, float* __restrict__ acc)
{
    int r = blockIdx.x * 256 + threadIdx.x;
    float lm = 0.f, lc = 0.f;
    if (r < BL) {
        float p = preds[r], lab = target[r];
        float msk = (lab > -0.9f) ? 1.f : 0.f;
        float d = p - lab;
        lm = d * d * msk;
        lc = msk;
        out[1 + r] = 1.f / (1.f + expf(-p));
    }
    lm = wave_sum64(lm);
    lc = wave_sum64(lc);
    __shared__ float sm[4], sc[4];
    int lane = threadIdx.x & 63, w = threadIdx.x >> 6;
    if (lane == 0) { sm[w] = lm; sc[w] = lc; }
    __syncthreads();
    if (threadIdx.x == 0) {
        atomicAdd(&acc[1], sm[0] + sm[1] + sm[2] + sm[3]);
        atomicAdd(&acc[2], sc[0] + sc[1] + sc[2] + sc[3]);
    }
}

__global__ void final_kernel(const float* __restrict__ acc, float* __restrict__ out)
{
    out[0] = acc[1] + acc[0] * 1e-5f;
    out[1 + BL] = acc[2];
}

extern "C" void kernel_launch(void* const* d_in, const int* in_sizes, int n_in,
                              void* d_out, int out_size, void* d_ws, size_t ws_size,
                              hipStream_t stream) {
    const int* q_data = (const int*)d_in[0];
    const int* qa_data = (const int*)d_in[1];
    const int* pid_data = (const int*)d_in[2];
    const float* matrix = (const float*)d_in[3];
    const float* target = (const float*)d_in[4];
    const float* q_emb = (const float*)d_in[5];
    const float* qa_emb = (const float*)d_in[6];
    const float* q_emb_diff = (const float*)d_in[7];
    const float* qa_emb_diff = (const float*)d_in[8];
    const float* diff_parm = (const float*)d_in[9];
    const float* w_ih = (const float*)d_in[10];
    const float* w_hh = (const float*)d_in[11];
    const float* b_ih = (const float*)d_in[12];
    const float* b_hh = (const float*)d_in[13];
    const float* fc_w = (const float*)d_in[14];
    const float* fc_b = (const float*)d_in[15];
    float* out = (float*)d_out;
    float* W = (float*)d_ws;

    float* acc = W + OFF_ACC;
    float* h0 = W + OFF_H0;
    float* Aq = W + OFF_AQ;
    float* Dq = W + OFF_DQ;
    float* Bqa = W + OFF_BQA;
    float* Cqa = W + OFF_CQA;
    float* wsum = W + OFF_WSUM;
    float* fcwT = W + OFF_FCWT;
    float* M2 = W + OFF_M2;
    float* mb = W + OFF_MB;
    float* xg = W + OFF_XG;
    float* gruT = W + OFF_GRU;
    int* qint = (int*)(W + OFF_QINT);
    int* qaint = (int*)(W + OFF_QAINT);
    float* pidf = W + OFF_PIDF;
    float* mval = W + OFF_MVAL;
    float* mc = W + OFF_MC;
    float* mi = W + OFF_MI;
    float* nmc = W + OFF_NMC;
    float* aa = W + OFF_AA;
    float* preds = W + OFF_PREDS;

    // zero the accumulators + h0 (contiguous at start of ws)
    hipMemsetAsync(W, 0, (4 + 32768) * sizeof(float), stream);

    prep_meta<<<50, 256, 0, stream>>>(q_data, qa_data, pid_data, diff_parm,
                                      qint, qaint, pidf, acc);
    wsum_kernel<<<G3, 256, 0, stream>>>(w_ih, wsum);
    transpose_kernel<<<dim3(16, 32), 256, 0, stream>>>(fc_w, fcwT, QQ, HH);

    // B_qa[a,g] = w_ih[:, :256] . qa_emb[a]  + b_ih ;  C_qa[a,g] = w_ih[:, :256] . qa_emb_diff[a]
    gemm_nt<<<dim3(24, 1), 256, 0, stream>>>(qa_emb, DD, w_ih, 2 * DD, Bqa, G3, 2, G3, DD, b_ih);
    gemm_nt<<<dim3(24, 1), 256, 0, stream>>>(qa_emb_diff, DD, w_ih, 2 * DD, Cqa, G3, 2, G3, DD, nullptr);
    // A_q = q_emb . (W1+W2)^T ; D_q = q_emb_diff . W2^T
    gemm_nt<<<dim3(24, 17), 256, 0, stream>>>(q_emb, DD, wsum, DD, Aq, G3, NQ + 1, G3, DD, nullptr);
    gemm_nt<<<dim3(24, 17), 256, 0, stream>>>(q_emb_diff, DD, w_ih + DD, 2 * DD, Dq, G3, NQ + 1, G3, DD, nullptr);
    // M2[k,h] = sum_q matrix[k,q] * fc_w[q,h]
    gemm_nt<<<dim3(8, 16), 256, 0, stream>>>(matrix, QQ, fcwT, QQ, M2, HH, QQ, HH, QQ, nullptr);
    mb_kernel<<<QQ, 256, 0, stream>>>(matrix, fc_b, mb);

    xg_kernel<<<BL, 256, 0, stream>>>(Aq, Bqa, Cqa, Dq, qint, qaint, pidf, xg);

    const float* hprev = h0;
    for (int t = 0; t < LL; ++t) {
        float* hout = gruT + (size_t)t * HH * BB;
        gru_step<<<256, 128, 0, stream>>>(hprev, xg + (size_t)t * BB * G3, w_hh, b_hh, hout);
        hprev = hout;
    }

    mval_kernel<<<LL, 64, 0, stream>>>(gruT, M2, mb, qint, mval);
    stats_kernel<<<BB, 256, 0, stream>>>(qint, qaint, mval, mc, mi, nmc, aa);
    dina_kernel<<<BB, 256, 0, stream>>>(qint, qaint, mval, mc, mi, nmc, aa, preds);
    loss_kernel<<<50, 256, 0, stream>>>(preds, target, out, acc);
    final_kernel<<<1, 1, 0, stream>>>(acc, out);
}